// Round 7
// baseline (292.196 us; speedup 1.0000x reference)
//
#include <hip/hip_runtime.h>

typedef __attribute__((ext_vector_type(8))) short bf16x8;
typedef __attribute__((ext_vector_type(8))) _Float16 f16x8;
typedef __attribute__((ext_vector_type(2))) __fp16 fp16v2;
typedef __attribute__((ext_vector_type(16))) float f32x16;

#define DDIM 128
#define NADDR 4096
#define VDIM 512
#define NT 32
#define ITERS (NADDR/NT)
#define BM 64
#define LOG2E 1.44269504088896340736f

// pack bf16-trunc(lo) into low short, bf16-trunc(hi) into high short
__device__ __forceinline__ unsigned pkhi(float hi, float lo){
  return __builtin_amdgcn_perm(__float_as_uint(hi), __float_as_uint(lo), 0x07060302u);
}

// ---------- pre-pass 1: addr f32 [4096][128] -> K tiles f16 ----------
// tile nt: element ts in [0,512): row = ts>>4, col = (ts&15)*8
__global__ __launch_bounds__(512)
void prep_k(const float* __restrict__ addr, _Float16* __restrict__ kt)
{
  const int nt = blockIdx.x, ts = threadIdx.x;
  const int r = ts >> 4, c8 = (ts & 15) * 8;
  const float* s = addr + (size_t)(nt*NT + r)*DDIM + c8;
  float4 a = *(const float4*)s;
  float4 b = *(const float4*)(s + 4);
  union { f16x8 v; fp16v2 h[4]; } u;
  u.h[0] = __builtin_amdgcn_cvt_pkrtz(a.x, a.y);
  u.h[1] = __builtin_amdgcn_cvt_pkrtz(a.z, a.w);
  u.h[2] = __builtin_amdgcn_cvt_pkrtz(b.x, b.y);
  u.h[3] = __builtin_amdgcn_cvt_pkrtz(b.z, b.w);
  ((f16x8*)kt)[(size_t)nt*512 + ts] = u.v;
}

// ---------- pre-pass 2: bank f32 [4096][512] -> V tiles bf16 transposed ----
// tile nt: thread t: vv = t&511, half = t>>9; 2 uint4 at index t*2+i hold
// bf16(bank[nt*32 + half*16 + 8i + {0..7}][vv]) packed in pairs.
__global__ __launch_bounds__(1024)
void prep_v(const float* __restrict__ bank, short* __restrict__ vt)
{
  const int nt = blockIdx.x, t = threadIdx.x;
  const int vv = t & 511, half = t >> 9;
  const float* src = bank + (size_t)(nt*NT + half*16) * VDIM + vv;
  float v[16];
  #pragma unroll
  for (int k = 0; k < 16; ++k) v[k] = src[(size_t)k * VDIM];
  uint4 p0, p1;
  p0.x = pkhi(v[1],  v[0]);  p0.y = pkhi(v[3],  v[2]);
  p0.z = pkhi(v[5],  v[4]);  p0.w = pkhi(v[7],  v[6]);
  p1.x = pkhi(v[9],  v[8]);  p1.y = pkhi(v[11], v[10]);
  p1.z = pkhi(v[13], v[12]); p1.w = pkhi(v[15], v[14]);
  uint4* dst = (uint4*)vt + ((size_t)nt*1024 + t)*2;
  dst[0] = p0; dst[1] = p1;
}

// ---------- main: 64m x 512v per block, 16 waves, S computed ONCE ----------
// Waves: wg = wave>>3 (m-group of 32), wv = wave&7 (v-group of 64).
// Duty waves (wave 0 and 9, on different SIMDs) compute S^T = K.Q^T for their
// m-group, exp+pack in-register (verified permlane path), and publish P to
// sP[b] in A-frag-ready layout (one b128 write). All 16 waves run PV(t-1)
// from sP[b^1]/sVt[b^1] in the same phase -> S || PV overlap across waves.
// No S redundancy (was 4x), no combine pass. ~110 VGPR -> 4 waves/SIMD.
__global__ __launch_bounds__(1024)
void soft_addr_kernel(const float* __restrict__ sel,
                      const _Float16* __restrict__ kt,
                      const short* __restrict__ vt,
                      float* __restrict__ out)
{
  __shared__ __align__(16) _Float16 sK[2][32][136];   // 17.4 KB
  __shared__ __align__(16) short  sVt[2][512][40];    // 80 KB
  __shared__ __align__(16) short  sP [2][BM][40];     // 10 KB
  __shared__ __align__(16) _Float16 sQ[BM][136];      // 17.4 KB
  __shared__ float sDen[BM];

  const int tid  = threadIdx.x;
  const int wave = tid >> 6;
  const int lane = tid & 63;
  const int h    = lane >> 5;
  const int c32  = lane & 31;
  const int wg   = wave >> 3;       // m-group (0/1)
  const int wv   = wave & 7;        // v-group (0..7)
  const bool duty = (wave == wg*8 + wg);   // waves 0, 9 -> SIMD 0, 1

  const int m0 = blockIdx.x * BM;

  // ---- prologue: stage Q (f16, log2e-scaled) ----
  {
    const int row = tid >> 4, seg = (tid & 15) * 8;
    const float* q = sel + (size_t)(m0 + row) * DDIM + seg;
    float4 a = *(const float4*)q;
    float4 b = *(const float4*)(q + 4);
    union { f16x8 v; fp16v2 hh[4]; } u;
    u.hh[0] = __builtin_amdgcn_cvt_pkrtz(a.x*LOG2E, a.y*LOG2E);
    u.hh[1] = __builtin_amdgcn_cvt_pkrtz(a.z*LOG2E, a.w*LOG2E);
    u.hh[2] = __builtin_amdgcn_cvt_pkrtz(b.x*LOG2E, b.y*LOG2E);
    u.hh[3] = __builtin_amdgcn_cvt_pkrtz(b.z*LOG2E, b.w*LOG2E);
    *(f16x8*)&sQ[row][seg] = u.v;
  }

  f32x16 oAcc[2];
  #pragma unroll
  for (int jv=0;jv<2;++jv)
    #pragma unroll
    for (int r=0;r<16;++r) oAcc[jv][r] = 0.f;
  float lacc = 0.f;

  const f16x8* kbase = (const f16x8*)kt;
  const uint4* vbase = (const uint4*)vt;

  f16x8 kfr;
  uint4 vfr[2];

  // prologue: load tile 0 staging regs
  if (tid < 512) kfr = kbase[tid];
  vfr[0] = vbase[(size_t)tid*2];
  vfr[1] = vbase[(size_t)tid*2 + 1];

  const int ksr = tid >> 4, ksc = (tid & 15) * 8;   // K staging map (tid<512)
  const int vsv = tid & 511, vsn = (tid >> 9) * 16; // V staging map

  for (int t = 0; t < ITERS; ++t){
    const int b = t & 1;

    // ---- stage tile t -> LDS buf b
    if (tid < 512) *(f16x8*)&sK[b][ksr][ksc] = kfr;
    *(uint4*)&sVt[b][vsv][vsn]     = vfr[0];
    *(uint4*)&sVt[b][vsv][vsn + 8] = vfr[1];

    __syncthreads();   // B1: tile t visible

    // ---- prefetch tile t+1 (consumed after B2 -> latency hides here)
    {
      const int n1 = (t+1) & (ITERS-1);
      if (tid < 512) kfr = kbase[(size_t)n1*512 + tid];
      vfr[0] = vbase[(size_t)n1*2048 + tid*2];
      vfr[1] = vbase[(size_t)n1*2048 + tid*2 + 1];
    }

    // ---- duty waves: S^T(t) = K.Q^T (32n x 32m, K=128), exp, pack, publish
    if (duty){
      f32x16 sAcc;
      #pragma unroll
      for (int r=0;r<16;++r) sAcc[r] = 0.f;
      #pragma unroll
      for (int ks=0; ks<8; ++ks){
        f16x8 aK = *(const f16x8*)&sK[b][c32][16*ks + 8*h];
        f16x8 aQ = *(const f16x8*)&sQ[32*wg + c32][16*ks + 8*h];
        sAcc = __builtin_amdgcn_mfma_f32_32x32x16_f16(aK, aQ, sAcc, 0,0,0);
      }
      unsigned dw[2][4];
      #pragma unroll
      for (int j=0;j<2;++j)
        #pragma unroll
        for (int i=0;i<4;++i){
          float pa = __builtin_amdgcn_exp2f(sAcc[8*j + 2*i]);
          float pb = __builtin_amdgcn_exp2f(sAcc[8*j + 2*i + 1]);
          unsigned ua = __float_as_uint(pa) & 0xffff0000u;
          unsigned ub = __float_as_uint(pb) & 0xffff0000u;
          lacc += __uint_as_float(ua);
          lacc += __uint_as_float(ub);
          dw[j][i] = pkhi(pb, pa);
        }
      #pragma unroll
      for (int j=0;j<2;++j){
        auto s02 = __builtin_amdgcn_permlane32_swap(dw[j][0], dw[j][2], false, false);
        auto s13 = __builtin_amdgcn_permlane32_swap(dw[j][1], dw[j][3], false, false);
        union { unsigned u[4]; bf16x8 v; } ap;
        ap.u[0] = s02[0]; ap.u[1] = s13[0]; ap.u[2] = s02[1]; ap.u[3] = s13[1];
        *(bf16x8*)&sP[b][32*wg + c32][16*j + 8*h] = ap.v;
      }
    }

    // ---- all waves: PV(t-1) from sP[b^1], sVt[b^1]
    if (t){
      __builtin_amdgcn_s_setprio(1);
      #pragma unroll
      for (int j=0;j<2;++j){
        bf16x8 aP = *(const bf16x8*)&sP[b^1][32*wg + c32][16*j + 8*h];
        #pragma unroll
        for (int jv=0;jv<2;++jv){
          bf16x8 bV = *(const bf16x8*)&sVt[b^1][wv*64 + 32*jv + c32][16*j + 8*h];
          oAcc[jv] = __builtin_amdgcn_mfma_f32_32x32x16_bf16(aP, bV, oAcc[jv], 0,0,0);
        }
      }
      __builtin_amdgcn_s_setprio(0);
    }

    __syncthreads();   // B2: sP(t) visible; old buffers safe to overwrite
  }

  // ---- epilogue: PV of last tile (index (ITERS-1)&1 = 1)
  #pragma unroll
  for (int j=0;j<2;++j){
    bf16x8 aP = *(const bf16x8*)&sP[1][32*wg + c32][16*j + 8*h];
    #pragma unroll
    for (int jv=0;jv<2;++jv){
      bf16x8 bV = *(const bf16x8*)&sVt[1][wv*64 + 32*jv + c32][16*j + 8*h];
      oAcc[jv] = __builtin_amdgcn_mfma_f32_32x32x16_bf16(aP, bV, oAcc[jv], 0,0,0);
    }
  }

  // ---- denominators: duty waves own rows; combine halves, publish
  if (duty){
    float tot = lacc + __shfl_xor(lacc, 32);
    if (lane < 32) sDen[32*wg + c32] = tot;
  }
  __syncthreads();

  // ---- divide + store (D: col v = c32, row m = (r&3)+8*(r>>2)+4h)
  #pragma unroll
  for (int r=0;r<16;++r){
    const int mrow = (r&3) + 8*(r>>2) + 4*h;
    const float inv = 1.0f / sDen[32*wg + mrow];
    float* op = out + (size_t)(m0 + 32*wg + mrow) * VDIM + wv*64 + c32;
    #pragma unroll
    for (int jv=0;jv<2;++jv)
      op[32*jv] = oAcc[jv][r] * inv;
  }
}

extern "C" void kernel_launch(void* const* d_in, const int* in_sizes, int n_in,
                              void* d_out, int out_size, void* d_ws, size_t ws_size,
                              hipStream_t stream) {
  const float* sel  = (const float*)d_in[0];   // [8,2048,128]
  const float* bank = (const float*)d_in[1];   // [4096,512]
  const float* addr = (const float*)d_in[2];   // [4096,128]
  float* out = (float*)d_out;                  // [8,2048,512]

  _Float16* kt = (_Float16*)d_ws;                      // 1 MB tiled f16 K
  short*    vt = (short*)((char*)d_ws + (1u<<20));     // 4 MB tiled bf16 V^T

  hipLaunchKernelGGL(prep_k, dim3(ITERS), dim3(512),  0, stream, addr, kt);
  hipLaunchKernelGGL(prep_v, dim3(ITERS), dim3(1024), 0, stream, bank, vt);
  hipLaunchKernelGGL(soft_addr_kernel, dim3(256), dim3(1024), 0, stream,
                     sel, kt, vt, out);
}

// Round 8
// 227.280 us; speedup vs baseline: 1.2856x; 1.2856x over previous
//
#include <hip/hip_runtime.h>

typedef __attribute__((ext_vector_type(8))) short bf16x8;
typedef __attribute__((ext_vector_type(8))) _Float16 f16x8;
typedef __attribute__((ext_vector_type(2))) __fp16 fp16v2;
typedef __attribute__((ext_vector_type(16))) float f32x16;

#define DDIM 128
#define NADDR 4096
#define VDIM 512
#define MTOT 16384
#define NT 32
#define NTILES (NADDR/NT)      // 128 n-tiles
#define NSPLIT 8               // pass-1 n-split (den partials)
#define LOG2E 1.44269504088896340736f

// pack bf16-trunc(lo) into low short, bf16-trunc(hi) into high short
__device__ __forceinline__ unsigned pkhi(float hi, float lo){
  return __builtin_amdgcn_perm(__float_as_uint(hi), __float_as_uint(lo), 0x07060302u);
}

// ---------- prep 1: addr f32 [4096][128] -> K tiles f16 ----------
// tile nt, element ts in [0,512): row = ts>>4, col = (ts&15)*8
__global__ __launch_bounds__(512)
void prep_k(const float* __restrict__ addr, _Float16* __restrict__ kt)
{
  const int nt = blockIdx.x, ts = threadIdx.x;
  const int r = ts >> 4, c8 = (ts & 15) * 8;
  const float* s = addr + (size_t)(nt*NT + r)*DDIM + c8;
  float4 a = *(const float4*)s;
  float4 b = *(const float4*)(s + 4);
  union { f16x8 v; fp16v2 h[4]; } u;
  u.h[0] = __builtin_amdgcn_cvt_pkrtz(a.x, a.y);
  u.h[1] = __builtin_amdgcn_cvt_pkrtz(a.z, a.w);
  u.h[2] = __builtin_amdgcn_cvt_pkrtz(b.x, b.y);
  u.h[3] = __builtin_amdgcn_cvt_pkrtz(b.z, b.w);
  ((f16x8*)kt)[(size_t)nt*512 + ts] = u.v;
}

// ---------- prep 2: bank f32 [4096][512] -> V B-frag tiles bf16 ----------
// tile nt: b128 idx = nt*2048 + (j*512 + v)*2 + h holds bf16 of
// bank[nt*32 + 16j + 8h + e][v], e=0..7 (HW-verified mapping, rounds 3-7)
__global__ __launch_bounds__(1024)
void prep_v(const float* __restrict__ bank, short* __restrict__ vt)
{
  const int nt = blockIdx.x, t = threadIdx.x;
  const int vv = t & 511, half = t >> 9;
  const float* src = bank + (size_t)(nt*NT + half*16) * VDIM + vv;
  float v[16];
  #pragma unroll
  for (int k = 0; k < 16; ++k) v[k] = src[(size_t)k * VDIM];
  uint4 p0, p1;
  p0.x = pkhi(v[1],  v[0]);  p0.y = pkhi(v[3],  v[2]);
  p0.z = pkhi(v[5],  v[4]);  p0.w = pkhi(v[7],  v[6]);
  p1.x = pkhi(v[9],  v[8]);  p1.y = pkhi(v[11], v[10]);
  p1.z = pkhi(v[13], v[12]); p1.w = pkhi(v[15], v[14]);
  uint4* dst = (uint4*)vt + ((size_t)nt*1024 + t)*2;
  dst[0] = p0; dst[1] = p1;
}

// ---------- pass 1: S = Q.K^T, exp2, store P (bf16 A-frags) + den partials --
// Block: 4 waves x 32m = 128 m-rows, n-range = nq*512 (16 n-tiles).
// Per wave-iter: verified S^T dual-chain (mfma_32x32x16_f16), exp2, pkhi,
// permlane32_swap -> A-frag apv[2]; store to pt; VALU lacc for den partial.
__global__ __launch_bounds__(256, 4)
void pass1_kernel(const float* __restrict__ sel,
                  const _Float16* __restrict__ kt,
                  short* __restrict__ pt,       // chunk-local P frags
                  float* __restrict__ den,      // [MTOT][8] partials
                  int m_off)
{
  __shared__ __align__(16) _Float16 sK[2][32][136];

  const int tid  = threadIdx.x;
  const int wave = tid >> 6;
  const int lane = tid & 63;
  const int h    = lane >> 5;
  const int c32  = lane & 31;

  const int nq  = blockIdx.x & 7;
  const int mbl = blockIdx.x >> 3;          // chunk-local m-block
  const int m0  = m_off + mbl * 128;        // global m base
  const int wm  = wave * 32;
  const int mtl = mbl * 4 + wave;           // chunk-local m-tile

  // ---- Q fragments (B operand: col m = c32, rows d = 16ks+8h+e), log2e-scaled
  f16x8 aQ[8];
  {
    const float* q = sel + (size_t)(m0 + wm + c32) * DDIM + 8*h;
    #pragma unroll
    for (int ks = 0; ks < 8; ++ks){
      float4 a = *(const float4*)(q + 16*ks);
      float4 b = *(const float4*)(q + 16*ks + 4);
      f16x8 f;
      f[0]=(_Float16)(a.x*LOG2E); f[1]=(_Float16)(a.y*LOG2E);
      f[2]=(_Float16)(a.z*LOG2E); f[3]=(_Float16)(a.w*LOG2E);
      f[4]=(_Float16)(b.x*LOG2E); f[5]=(_Float16)(b.y*LOG2E);
      f[6]=(_Float16)(b.z*LOG2E); f[7]=(_Float16)(b.w*LOG2E);
      aQ[ks] = f;
    }
  }

  f32x16 zc;
  #pragma unroll
  for (int r=0;r<16;++r) zc[r] = 0.f;
  asm volatile("" : "+v"(zc));

  float lacc = 0.f;

  const int kr = tid >> 4, kc = (tid & 15) * 8;
  const f16x8* kbase = (const f16x8*)kt + (size_t)(nq*16)*512;
  bf16x8* pbase = (bf16x8*)pt + (size_t)mtl * NTILES * 128;  // 64 lanes * 2

  f16x8 kfr[2];
  kfr[0] = kbase[tid];
  kfr[1] = kbase[tid + 256];

  for (int t = 0; t < 16; ++t){
    const int b = t & 1;

    *(f16x8*)&sK[b][kr]     [kc] = kfr[0];
    *(f16x8*)&sK[b][kr + 16][kc] = kfr[1];
    __syncthreads();

    // prefetch next K tile (wraps harmlessly on last iter)
    {
      const int t1 = (t+1) & 15;
      kfr[0] = kbase[(size_t)t1*512 + tid];
      kfr[1] = kbase[(size_t)t1*512 + tid + 256];
    }

    // S^T = K.Q^T : two independent 4-chains
    __builtin_amdgcn_s_setprio(1);
    f32x16 sAcc0, sAcc1;
    {
      f16x8 aK0 = *(const f16x8*)&sK[b][c32][8*h];
      f16x8 aK1 = *(const f16x8*)&sK[b][c32][16 + 8*h];
      sAcc0 = __builtin_amdgcn_mfma_f32_32x32x16_f16(aK0, aQ[0], zc, 0,0,0);
      sAcc1 = __builtin_amdgcn_mfma_f32_32x32x16_f16(aK1, aQ[1], zc, 0,0,0);
    }
    #pragma unroll
    for (int ks=1; ks<4; ++ks){
      f16x8 aK0 = *(const f16x8*)&sK[b][c32][16*(2*ks)   + 8*h];
      f16x8 aK1 = *(const f16x8*)&sK[b][c32][16*(2*ks+1) + 8*h];
      sAcc0 = __builtin_amdgcn_mfma_f32_32x32x16_f16(aK0, aQ[2*ks],   sAcc0, 0,0,0);
      sAcc1 = __builtin_amdgcn_mfma_f32_32x32x16_f16(aK1, aQ[2*ks+1], sAcc1, 0,0,0);
    }
    __builtin_amdgcn_s_setprio(0);

    // P = 2^S, bf16-trunc; den partial accumulates the truncated values
    unsigned dw[2][4];
    #pragma unroll
    for (int j=0;j<2;++j)
      #pragma unroll
      for (int i=0;i<4;++i){
        float pa = __builtin_amdgcn_exp2f(sAcc0[8*j + 2*i]     + sAcc1[8*j + 2*i]);
        float pb = __builtin_amdgcn_exp2f(sAcc0[8*j + 2*i + 1] + sAcc1[8*j + 2*i + 1]);
        lacc += __uint_as_float(__float_as_uint(pa) & 0xffff0000u);
        lacc += __uint_as_float(__float_as_uint(pb) & 0xffff0000u);
        dw[j][i] = pkhi(pb, pa);
      }

    // pack to A-frags (verified permlane path) and store to pt
    const int nt = nq*16 + t;
    #pragma unroll
    for (int j=0;j<2;++j){
      auto s02 = __builtin_amdgcn_permlane32_swap(dw[j][0], dw[j][2], false, false);
      auto s13 = __builtin_amdgcn_permlane32_swap(dw[j][1], dw[j][3], false, false);
      union { unsigned u[4]; bf16x8 v; } ap;
      ap.u[0] = s02[0]; ap.u[1] = s13[0]; ap.u[2] = s02[1]; ap.u[3] = s13[1];
      pbase[((size_t)nt*64 + lane)*2 + j] = ap.v;
    }
  }

  // den partial: lane holds rows m = c32 (half-waves cover n-halves)
  float tot = lacc + __shfl_xor(lacc, 32);
  if (lane < 32)
    den[(size_t)(m0 + wm + c32)*8 + nq] = tot;
}

// ---------- pass 2: O = P.V — pure streaming GEMM, no LDS, no barriers ----
// Block: 4 waves, 128m x 128v. Wave: 32m x 128v, K=4096 over 128 n-tiles.
// A-frags from pt (lane-direct), B-frags from vt (lane-direct, L1-shared
// across the block's 4 waves). 1-deep named-register prefetch.
#define P2_LOAD(NTI, A0, A1, B)                                          \
  { const size_t nto = (size_t)(NTI);                                    \
    A0 = pa[(nto*64 + lane)*2];                                          \
    A1 = pa[(nto*64 + lane)*2 + 1];                                      \
    _Pragma("unroll")                                                    \
    for (int j=0;j<2;++j)                                                \
      _Pragma("unroll")                                                  \
      for (int jv=0;jv<4;++jv)                                           \
        B[j*4+jv] = vb[nto*2048 + (size_t)((j*512) + v0 + 32*jv + c32)*2 + h]; }

#define P2_MM(A0, A1, B)                                                 \
  { _Pragma("unroll")                                                    \
    for (int jv=0;jv<4;++jv)                                             \
      oAcc[jv] = __builtin_amdgcn_mfma_f32_32x32x16_bf16(A0, B[jv],      \
                                                         oAcc[jv], 0,0,0); \
    _Pragma("unroll")                                                    \
    for (int jv=0;jv<4;++jv)                                             \
      oAcc[jv] = __builtin_amdgcn_mfma_f32_32x32x16_bf16(A1, B[4+jv],    \
                                                         oAcc[jv], 0,0,0); }

__global__ __launch_bounds__(256, 2)
void pass2_kernel(const short* __restrict__ pt,
                  const short* __restrict__ vt,
                  const float* __restrict__ den,
                  float* __restrict__ out,
                  int m_off)
{
  const int tid  = threadIdx.x;
  const int wave = tid >> 6;
  const int lane = tid & 63;
  const int h    = lane >> 5;
  const int c32  = lane & 31;

  const int vblk = blockIdx.x & 3;
  const int mb   = blockIdx.x >> 2;       // chunk-local m-block
  const int v0   = vblk * 128;
  const int mtl  = mb * 4 + wave;         // chunk-local m-tile
  const int mg   = m_off + mtl * 32;      // global m base of this wave

  const bf16x8* pa = (const bf16x8*)pt + (size_t)mtl * NTILES * 128;
  const bf16x8* vb = (const bf16x8*)vt;

  f32x16 oAcc[4];
  #pragma unroll
  for (int jv=0;jv<4;++jv)
    #pragma unroll
    for (int r=0;r<16;++r) oAcc[jv][r] = 0.f;

  bf16x8 A0a, A1a, Ba[8];
  bf16x8 A0b, A1b, Bb[8];

  P2_LOAD(0, A0a, A1a, Ba);
  for (int nt = 0; nt < NTILES; nt += 2){
    P2_LOAD(nt+1, A0b, A1b, Bb);
    P2_MM(A0a, A1a, Ba);
    if (nt + 2 < NTILES) P2_LOAD(nt+2, A0a, A1a, Ba);
    P2_MM(A0b, A1b, Bb);
  }

  // epilogue: den = sum of 8 partials; divide + store
  #pragma unroll
  for (int r=0;r<16;++r){
    const int mrow = (r&3) + 8*(r>>2) + 4*h;
    const int m = mg + mrow;
    float4 d0 = *(const float4*)&den[(size_t)m*8];
    float4 d1 = *(const float4*)&den[(size_t)m*8 + 4];
    const float inv = 1.0f / (d0.x+d0.y+d0.z+d0.w + d1.x+d1.y+d1.z+d1.w);
    float* op = out + (size_t)m * VDIM + v0 + c32;
    #pragma unroll
    for (int jv=0;jv<4;++jv)
      op[32*jv] = oAcc[jv][r] * inv;
  }
}

extern "C" void kernel_launch(void* const* d_in, const int* in_sizes, int n_in,
                              void* d_out, int out_size, void* d_ws, size_t ws_size,
                              hipStream_t stream) {
  const float* sel  = (const float*)d_in[0];   // [8,2048,128]
  const float* bank = (const float*)d_in[1];   // [4096,512]
  const float* addr = (const float*)d_in[2];   // [4096,128]
  float* out = (float*)d_out;                  // [8,2048,512]

  char* ws = (char*)d_ws;
  _Float16* kt  = (_Float16*)ws;                 // 1 MB   tiled f16 K
  short*    vt  = (short*)(ws + (1u<<20));       // 4 MB   tiled bf16 V B-frags
  float*    den = (float*)(ws + (5u<<20));       // 512 KB den partials [m][8]
  short*    pt  = (short*)(ws + (6u<<20));       // P frags (chunked)

  // adaptive m-chunking so P fits the workspace (full = 140 MB)
  int CM = MTOT;
  while (CM > 2048 && (size_t)(6u<<20) + (size_t)CM*NADDR*2 > ws_size) CM >>= 1;

  hipLaunchKernelGGL(prep_k, dim3(NTILES), dim3(512),  0, stream, addr, kt);
  hipLaunchKernelGGL(prep_v, dim3(NTILES), dim3(1024), 0, stream, bank, vt);
  for (int mo = 0; mo < MTOT; mo += CM){
    hipLaunchKernelGGL(pass1_kernel, dim3(CM/16), dim3(256), 0, stream,
                       sel, kt, pt, den, mo);
    hipLaunchKernelGGL(pass2_kernel, dim3(CM/32), dim3(256), 0, stream,
                       pt, vt, den, out, mo);
  }
}